// Round 5
// baseline (327.185 us; speedup 1.0000x reference)
//
#include <hip/hip_runtime.h>
#include <math.h>

#define S_   2048
#define D_   1024
#define H_   16
#define HD_  64
#define BH_  64
#define TOK_ 8192

typedef __attribute__((ext_vector_type(8))) short  short8;
typedef __attribute__((ext_vector_type(4))) float  floatx4;

__device__ __forceinline__ short f2bf(float f) {
  union { float f; unsigned u; } c; c.f = f;
  unsigned u = c.u;
  u += 0x7fffu + ((u >> 16) & 1u);   // RNE
  return (short)(u >> 16);
}

__device__ __forceinline__ void gload16(const void* g, void* l) {
  __builtin_amdgcn_global_load_lds((const __attribute__((address_space(1))) void*)g,
                                   (__attribute__((address_space(3))) void*)l, 16, 0, 0);
}

// ---------------- fp32 -> bf16 elementwise (x) ----------------
__global__ void cvt_x_kernel(const float* __restrict__ in, short* __restrict__ out, int n8) {
  int i = blockIdx.x * blockDim.x + threadIdx.x;
  if (i >= n8) return;
  const float4* p = (const float4*)in;
  float4 a = p[i * 2], b = p[i * 2 + 1];
  short8 o;
  o[0] = f2bf(a.x); o[1] = f2bf(a.y); o[2] = f2bf(a.z); o[3] = f2bf(a.w);
  o[4] = f2bf(b.x); o[5] = f2bf(b.y); o[6] = f2bf(b.z); o[7] = f2bf(b.w);
  ((short8*)out)[i] = o;
}

// ---------------- W [R][C] fp32 -> Wt [C][R] bf16 ----------------
__global__ void tconv_kernel(const float* __restrict__ in, short* __restrict__ out, int R, int C) {
  __shared__ float t[32][33];
  int tx = threadIdx.x, ty = threadIdx.y;
  int c0 = blockIdx.x * 32, r0 = blockIdx.y * 32;
#pragma unroll
  for (int i = 0; i < 4; ++i)
    t[ty + i * 8][tx] = in[(r0 + ty + i * 8) * C + c0 + tx];
  __syncthreads();
#pragma unroll
  for (int i = 0; i < 4; ++i)
    out[(c0 + ty + i * 8) * R + r0 + tx] = f2bf(t[tx][ty + i * 8]);
}

// ---------------- v [bh][s][d] -> vt [bh][d][s] (bf16) ----------------
__global__ void tv_kernel(const short* __restrict__ vb, short* __restrict__ vtb) {
  __shared__ short t[32][33];
  int tx = threadIdx.x, ty = threadIdx.y;
  int bh = blockIdx.z;
  int d0 = blockIdx.x * 32, s0 = blockIdx.y * 32;
  const short* src = vb + bh * S_ * HD_;
  short* dst = vtb + bh * HD_ * S_;
#pragma unroll
  for (int i = 0; i < 4; ++i)
    t[ty + i * 8][tx] = src[(s0 + ty + i * 8) * HD_ + d0 + tx];
  __syncthreads();
#pragma unroll
  for (int i = 0; i < 4; ++i)
    dst[(d0 + ty + i * 8) * S_ + s0 + tx] = t[tx][ty + i * 8];
}

// ---------------- GEMM1: qkv = x @ Wqkv, scatter to q/k/v [bh][s][d] ----------------
// q is pre-scaled by (1/sqrt(hd))*log2(e) = 0.125*1.442695 so attn uses exp2.
__global__ __launch_bounds__(256) void gemm_qkv_kernel(
    const short* __restrict__ A, const short* __restrict__ Bt,
    short* __restrict__ qb, short* __restrict__ kb, short* __restrict__ vb) {
  __shared__ short sA[128 * 32];
  __shared__ short sB[128 * 32];
  const int tid = threadIdx.x;
  const int lane = tid & 63, wid = tid >> 6;
  const int wm = wid >> 1, wn = wid & 1;
  const int lr = lane & 15, lg = lane >> 4;
  const int m0 = blockIdx.x * 128, n0 = blockIdx.y * 128;
  floatx4 acc[4][4] = {};
  const int f1 = tid * 16;
  const int rS1 = f1 >> 6, cS1 = (f1 & 63) >> 1;
  const int f2 = f1 + 4096;
  const int rS2 = f2 >> 6, cS2 = (f2 & 63) >> 1;
  for (int kt = 0; kt < 32; ++kt) {
    const int k0 = kt * 32;
    __syncthreads();
    gload16(&A[(m0 + rS1) * 1024 + k0 + cS1], (char*)sA + f1);
    gload16(&A[(m0 + rS2) * 1024 + k0 + cS2], (char*)sA + f2);
    gload16(&Bt[(n0 + rS1) * 1024 + k0 + cS1], (char*)sB + f1);
    gload16(&Bt[(n0 + rS2) * 1024 + k0 + cS2], (char*)sB + f2);
    __syncthreads();
    short8 af[4], bfv[4];
#pragma unroll
    for (int mf = 0; mf < 4; ++mf)
      af[mf] = *(const short8*)&sA[(wm * 64 + mf * 16 + lr) * 32 + lg * 8];
#pragma unroll
    for (int nf = 0; nf < 4; ++nf)
      bfv[nf] = *(const short8*)&sB[(wn * 64 + nf * 16 + lr) * 32 + lg * 8];
#pragma unroll
    for (int mf = 0; mf < 4; ++mf)
#pragma unroll
      for (int nf = 0; nf < 4; ++nf)
        acc[mf][nf] = __builtin_amdgcn_mfma_f32_16x16x32_bf16(af[mf], bfv[nf], acc[mf][nf], 0, 0, 0);
  }
  const int sec = n0 >> 10;  // 0=q 1=k 2=v (128 | 1024 so uniform per block)
  short* dst = sec == 0 ? qb : (sec == 1 ? kb : vb);
  const float scale = (sec == 0) ? 0.18033688011112042f : 1.0f;
#pragma unroll
  for (int mf = 0; mf < 4; ++mf) {
#pragma unroll
    for (int nf = 0; nf < 4; ++nf) {
      const int col = n0 + wn * 64 + nf * 16 + lr;
      const int w = col & 1023;
      const int h = w >> 6, d = w & 63;
#pragma unroll
      for (int r = 0; r < 4; ++r) {
        const int token = m0 + wm * 64 + mf * 16 + lg * 4 + r;
        const int b = token >> 11, s = token & 2047;
        dst[(((b << 4) | h) * 2048 + s) * 64 + d] = f2bf(acc[mf][nf][r] * scale);
      }
    }
  }
}

// ---------------- GEMM2: out = att @ Wproj + bias (fp32 out) ----------------
__global__ __launch_bounds__(256) void gemm_proj_kernel(
    const short* __restrict__ A, const short* __restrict__ Bt,
    const float* __restrict__ bias, float* __restrict__ out) {
  __shared__ short sA[128 * 32];
  __shared__ short sB[128 * 32];
  const int tid = threadIdx.x;
  const int lane = tid & 63, wid = tid >> 6;
  const int wm = wid >> 1, wn = wid & 1;
  const int lr = lane & 15, lg = lane >> 4;
  const int m0 = blockIdx.x * 128, n0 = blockIdx.y * 128;
  floatx4 acc[4][4] = {};
  const int f1 = tid * 16;
  const int rS1 = f1 >> 6, cS1 = (f1 & 63) >> 1;
  const int f2 = f1 + 4096;
  const int rS2 = f2 >> 6, cS2 = (f2 & 63) >> 1;
  for (int kt = 0; kt < 32; ++kt) {
    const int k0 = kt * 32;
    __syncthreads();
    gload16(&A[(m0 + rS1) * 1024 + k0 + cS1], (char*)sA + f1);
    gload16(&A[(m0 + rS2) * 1024 + k0 + cS2], (char*)sA + f2);
    gload16(&Bt[(n0 + rS1) * 1024 + k0 + cS1], (char*)sB + f1);
    gload16(&Bt[(n0 + rS2) * 1024 + k0 + cS2], (char*)sB + f2);
    __syncthreads();
    short8 af[4], bfv[4];
#pragma unroll
    for (int mf = 0; mf < 4; ++mf)
      af[mf] = *(const short8*)&sA[(wm * 64 + mf * 16 + lr) * 32 + lg * 8];
#pragma unroll
    for (int nf = 0; nf < 4; ++nf)
      bfv[nf] = *(const short8*)&sB[(wn * 64 + nf * 16 + lr) * 32 + lg * 8];
#pragma unroll
    for (int mf = 0; mf < 4; ++mf)
#pragma unroll
      for (int nf = 0; nf < 4; ++nf)
        acc[mf][nf] = __builtin_amdgcn_mfma_f32_16x16x32_bf16(af[mf], bfv[nf], acc[mf][nf], 0, 0, 0);
  }
#pragma unroll
  for (int mf = 0; mf < 4; ++mf) {
#pragma unroll
    for (int nf = 0; nf < 4; ++nf) {
      const int col = n0 + wn * 64 + nf * 16 + lr;
      const float bv = bias[col];
#pragma unroll
      for (int r = 0; r < 4; ++r) {
        const int row = m0 + wm * 64 + mf * 16 + lg * 4 + r;
        out[row * 1024 + col] = acc[mf][nf][r] + bv;
      }
    }
  }
}

// ---------------- Flash attention (causal), bf16 in/out ----------------
// v3: 1024 blocks (4 waves x 16 q-rows each; qt paired with 31-qt -> uniform
// 33 KV tiles/block); denominator via MFMA against a ones-B-frag (no sum
// shuffles); exp2-domain scores (q pre-scaled by 0.125*log2e); defer-max
// rescale skip (THR=8, log2 units); double-buffered K/VT staging; XCD swizzle.
__global__ __launch_bounds__(256) void attn_kernel(
    const short* __restrict__ qb, const short* __restrict__ kb,
    const short* __restrict__ vtb, short* __restrict__ attb) {
  __shared__ short sK[2][64 * 64];
  __shared__ short sVT[2][64 * 64];
  __shared__ short sP[4][16 * 64];
  const int tid = threadIdx.x;
  const int lane = tid & 63, wid = tid >> 6;
  const int lr = lane & 15, lg = lane >> 4;

  // XCD swizzle: 8 consecutive bh per XCD (K+V = 4MB = one L2).
  const int bid = blockIdx.x;                 // 0..1023
  const int wgid = (bid & 7) * 128 + (bid >> 3);
  const int bh = wgid >> 4;                   // 0..63
  const int qx = wgid & 15;                   // 0..15

  const char* kbase = (const char*)(kb + bh * S_ * HD_);
  const char* vtbase = (const char*)(vtb + bh * HD_ * S_);
  const short* qbase = qb + bh * S_ * HD_;
  char* pbase = (char*)&sP[wid][0];
  const int b = bh >> 4, h = bh & 15;

  const int f1 = tid * 16;
  const int ro1 = f1 >> 7, cb1 = f1 & 127;
  const int sc1 = cb1 ^ ((ro1 & 7) << 4);
  const int f2 = f1 + 4096;
  const int ro2 = f2 >> 7, cb2 = f2 & 127;
  const int sc2 = cb2 ^ ((ro2 & 7) << 4);

  short8 vones;
#pragma unroll
  for (int j = 0; j < 8; ++j) vones[j] = (short)0x3F80;  // bf16 1.0

#pragma unroll 1
  for (int half = 0; half < 2; ++half) {
    const int qt = half ? (31 - qx) : qx;    // 0..31
    const int qw = qt * 64 + wid * 16;

    short8 qf[2];
#pragma unroll
    for (int kf = 0; kf < 2; ++kf)
      qf[kf] = *(const short8*)&qbase[(qw + lr) * 64 + kf * 32 + lg * 8];

    floatx4 acc_o[4] = {};
    floatx4 acc_den = {};
    float mrun[4];
#pragma unroll
    for (int i = 0; i < 4; ++i) mrun[i] = -1e30f;

    const int ntiles = qt + 1;

    // prologue: stage tile 0 into buf 0
    {
      char* dK = (char*)sK[0];
      char* dV = (char*)sVT[0];
      gload16(kbase + ro1 * 128 + sc1, dK + f1);
      gload16(kbase + ro2 * 128 + sc2, dK + f2);
      gload16(vtbase + ro1 * 4096 + sc1, dV + f1);
      gload16(vtbase + ro2 * 4096 + sc2, dV + f2);
      asm volatile("s_waitcnt vmcnt(0)" ::: "memory");
      __builtin_amdgcn_s_barrier();
      __builtin_amdgcn_sched_barrier(0);
    }

    int cur = 0;
#pragma unroll 1
    for (int t = 0; t < ntiles; ++t) {
      if (t + 1 < ntiles) {
        const int key0n = (t + 1) * 64;
        char* dK = (char*)sK[cur ^ 1];
        char* dV = (char*)sVT[cur ^ 1];
        gload16(kbase + (key0n + ro1) * 128 + sc1, dK + f1);
        gload16(kbase + (key0n + ro2) * 128 + sc2, dK + f2);
        gload16(vtbase + ro1 * 4096 + key0n * 2 + sc1, dV + f1);
        gload16(vtbase + ro2 * 4096 + key0n * 2 + sc2, dV + f2);
      }
      const int key0 = t * 64;
      const char* cK = (const char*)sK[cur];
      const char* cV = (const char*)sVT[cur];

      // S = Q K^T  (rows q=16, cols key=64)
      floatx4 s_acc[4] = {};
      __builtin_amdgcn_s_setprio(1);
#pragma unroll
      for (int nf = 0; nf < 4; ++nf) {
#pragma unroll
        for (int kf = 0; kf < 2; ++kf) {
          const int row = nf * 16 + lr;
          const int cb = kf * 64 + lg * 16;
          short8 kfrag = *(const short8*)(cK + row * 128 + (cb ^ ((row & 7) << 4)));
          s_acc[nf] = __builtin_amdgcn_mfma_f32_16x16x32_bf16(qf[kf], kfrag, s_acc[nf], 0, 0, 0);
        }
      }
      __builtin_amdgcn_s_setprio(0);

      const bool needmask = (key0 + 63 > qw);  // wave-uniform
      // mask + per-row max (in-register then 16-lane butterfly)
      float mx[4];
      bool need = false;
#pragma unroll
      for (int r = 0; r < 4; ++r) {
        const int qrow = qw + lg * 4 + r;
        if (needmask) {
#pragma unroll
          for (int nf = 0; nf < 4; ++nf)
            if (key0 + nf * 16 + lr > qrow) s_acc[nf][r] = -1e30f;
        }
        float m01 = fmaxf(s_acc[0][r], s_acc[1][r]);
        float m23 = fmaxf(s_acc[2][r], s_acc[3][r]);
        float mxl = fmaxf(m01, m23);
#pragma unroll
        for (int m = 1; m < 16; m <<= 1) mxl = fmaxf(mxl, __shfl_xor(mxl, m));
        mx[r] = mxl;
        need = need || (mxl > mrun[r] + 8.f);
      }
      if (__any(need)) {
#pragma unroll
        for (int r = 0; r < 4; ++r) {
          const float mnew = fmaxf(mrun[r], mx[r]);
          const float al = exp2f(mrun[r] - mnew);
          mrun[r] = mnew;
          acc_den[r] *= al;
#pragma unroll
          for (int nfd = 0; nfd < 4; ++nfd) acc_o[nfd][r] *= al;
        }
      }
      // P = exp2(S - m) -> bf16 into wave-private swizzled LDS
#pragma unroll
      for (int r = 0; r < 4; ++r) {
        const int qlocal = lg * 4 + r;
        const int sw = (qlocal & 7) << 4;
#pragma unroll
        for (int nf = 0; nf < 4; ++nf) {
          const float p = exp2f(s_acc[nf][r] - mrun[r]);
          *(short*)(pbase + qlocal * 128 + ((nf * 32 + lr * 2) ^ sw)) = f2bf(p);
        }
      }

      // O += P @ V ; den += P @ 1  (A = P from LDS, B = V^T rows = d)
      __builtin_amdgcn_s_setprio(1);
#pragma unroll
      for (int kf2 = 0; kf2 < 2; ++kf2) {
        const short8 pf = *(const short8*)(pbase + lr * 128 + ((kf2 * 64 + lg * 16) ^ ((lr & 7) << 4)));
        acc_den = __builtin_amdgcn_mfma_f32_16x16x32_bf16(pf, vones, acc_den, 0, 0, 0);
#pragma unroll
        for (int nfd = 0; nfd < 4; ++nfd) {
          const int rowv = nfd * 16 + lr;
          const int cbv = kf2 * 64 + lg * 16;
          short8 vfrag = *(const short8*)(cV + rowv * 128 + (cbv ^ ((rowv & 7) << 4)));
          acc_o[nfd] = __builtin_amdgcn_mfma_f32_16x16x32_bf16(pf, vfrag, acc_o[nfd], 0, 0, 0);
        }
      }
      __builtin_amdgcn_s_setprio(0);

      __builtin_amdgcn_sched_barrier(0);
      asm volatile("s_waitcnt vmcnt(0)" ::: "memory");
      __builtin_amdgcn_s_barrier();
      __builtin_amdgcn_sched_barrier(0);
      cur ^= 1;
    }

    // epilogue -> att [token][h*64+d] bf16
#pragma unroll
    for (int nfd = 0; nfd < 4; ++nfd) {
#pragma unroll
      for (int r = 0; r < 4; ++r) {
        const float o = acc_o[nfd][r] / acc_den[r];
        const int qrow = qw + lg * 4 + r;
        const int d = nfd * 16 + lr;
        attb[(b * 2048 + qrow) * 1024 + h * 64 + d] = f2bf(o);
      }
    }
  }
}

extern "C" void kernel_launch(void* const* d_in, const int* in_sizes, int n_in,
                              void* d_out, int out_size, void* d_ws, size_t ws_size,
                              hipStream_t stream) {
  (void)in_sizes; (void)n_in; (void)out_size; (void)ws_size;
  const float* x = (const float*)d_in[0];
  const float* Wqkv = (const float*)d_in[1];
  const float* Wproj = (const float*)d_in[2];
  const float* bproj = (const float*)d_in[3];
  float* out = (float*)d_out;

  char* w = (char*)d_ws;
  short* xb     = (short*)(w + 0);          // 16 MiB  [8192][1024]
  short* wqkvT  = (short*)(w + 16777216);   // 6 MiB   [3072][1024]
  short* wprojT = (short*)(w + 23068672);   // 2 MiB   [1024][1024]
  short* qb     = (short*)(w + 25165824);   // 16 MiB  [bh][s][d]
  short* kb     = (short*)(w + 41943040);   // 16 MiB
  short* vb     = (short*)(w + 58720256);   // 16 MiB
  short* vtb    = (short*)(w + 75497472);   // 16 MiB  [bh][d][s]
  short* attb   = (short*)(w + 92274688);   // 16 MiB  [8192][1024]

  cvt_x_kernel<<<4096, 256, 0, stream>>>(x, xb, TOK_ * D_ / 8);
  tconv_kernel<<<dim3(96, 32), dim3(32, 8), 0, stream>>>(Wqkv, wqkvT, 1024, 3072);
  tconv_kernel<<<dim3(32, 32), dim3(32, 8), 0, stream>>>(Wproj, wprojT, 1024, 1024);
  gemm_qkv_kernel<<<dim3(64, 24), 256, 0, stream>>>(xb, wqkvT, qb, kb, vb);
  tv_kernel<<<dim3(2, 64, 64), dim3(32, 8), 0, stream>>>(vb, vtb);
  attn_kernel<<<1024, 256, 0, stream>>>(qb, kb, vtb, attb);
  gemm_proj_kernel<<<dim3(64, 8), 256, 0, stream>>>(attb, wprojT, bproj, out);
}

// Round 6
// 262.196 us; speedup vs baseline: 1.2479x; 1.2479x over previous
//
#include <hip/hip_runtime.h>
#include <math.h>

#define S_   2048
#define D_   1024
#define H_   16
#define HD_  64
#define BH_  64
#define TOK_ 8192

typedef __attribute__((ext_vector_type(8))) short  short8;
typedef __attribute__((ext_vector_type(4))) float  floatx4;

__device__ __forceinline__ short f2bf(float f) {
  union { float f; unsigned u; } c; c.f = f;
  unsigned u = c.u;
  u += 0x7fffu + ((u >> 16) & 1u);   // RNE
  return (short)(u >> 16);
}

__device__ __forceinline__ void gload16(const void* g, void* l) {
  __builtin_amdgcn_global_load_lds((const __attribute__((address_space(1))) void*)g,
                                   (__attribute__((address_space(3))) void*)l, 16, 0, 0);
}

// ---------------- fp32 -> bf16 elementwise (x) ----------------
__global__ void cvt_x_kernel(const float* __restrict__ in, short* __restrict__ out, int n8) {
  int i = blockIdx.x * blockDim.x + threadIdx.x;
  if (i >= n8) return;
  const float4* p = (const float4*)in;
  float4 a = p[i * 2], b = p[i * 2 + 1];
  short8 o;
  o[0] = f2bf(a.x); o[1] = f2bf(a.y); o[2] = f2bf(a.z); o[3] = f2bf(a.w);
  o[4] = f2bf(b.x); o[5] = f2bf(b.y); o[6] = f2bf(b.z); o[7] = f2bf(b.w);
  ((short8*)out)[i] = o;
}

// ---------------- W [R][C] fp32 -> Wt [C][R] bf16 ----------------
__global__ void tconv_kernel(const float* __restrict__ in, short* __restrict__ out, int R, int C) {
  __shared__ float t[32][33];
  int tx = threadIdx.x, ty = threadIdx.y;
  int c0 = blockIdx.x * 32, r0 = blockIdx.y * 32;
#pragma unroll
  for (int i = 0; i < 4; ++i)
    t[ty + i * 8][tx] = in[(r0 + ty + i * 8) * C + c0 + tx];
  __syncthreads();
#pragma unroll
  for (int i = 0; i < 4; ++i)
    out[(c0 + ty + i * 8) * R + r0 + tx] = f2bf(t[tx][ty + i * 8]);
}

// ---------------- v [bh][s][d] -> vt [bh][d][s] (bf16) ----------------
__global__ void tv_kernel(const short* __restrict__ vb, short* __restrict__ vtb) {
  __shared__ short t[32][33];
  int tx = threadIdx.x, ty = threadIdx.y;
  int bh = blockIdx.z;
  int d0 = blockIdx.x * 32, s0 = blockIdx.y * 32;
  const short* src = vb + bh * S_ * HD_;
  short* dst = vtb + bh * HD_ * S_;
#pragma unroll
  for (int i = 0; i < 4; ++i)
    t[ty + i * 8][tx] = src[(s0 + ty + i * 8) * HD_ + d0 + tx];
  __syncthreads();
#pragma unroll
  for (int i = 0; i < 4; ++i)
    dst[(d0 + ty + i * 8) * S_ + s0 + tx] = t[tx][ty + i * 8];
}

// ---------------- GEMM1: qkv = x @ Wqkv, scatter to q/k/v [bh][s][d] ----------------
// q is pre-scaled by (1/sqrt(hd))*log2(e) so attn uses exp2.
__global__ __launch_bounds__(256) void gemm_qkv_kernel(
    const short* __restrict__ A, const short* __restrict__ Bt,
    short* __restrict__ qb, short* __restrict__ kb, short* __restrict__ vb) {
  __shared__ short sA[128 * 32];
  __shared__ short sB[128 * 32];
  const int tid = threadIdx.x;
  const int lane = tid & 63, wid = tid >> 6;
  const int wm = wid >> 1, wn = wid & 1;
  const int lr = lane & 15, lg = lane >> 4;
  const int m0 = blockIdx.x * 128, n0 = blockIdx.y * 128;
  floatx4 acc[4][4] = {};
  const int f1 = tid * 16;
  const int rS1 = f1 >> 6, cS1 = (f1 & 63) >> 1;
  const int f2 = f1 + 4096;
  const int rS2 = f2 >> 6, cS2 = (f2 & 63) >> 1;
  for (int kt = 0; kt < 32; ++kt) {
    const int k0 = kt * 32;
    __syncthreads();
    gload16(&A[(m0 + rS1) * 1024 + k0 + cS1], (char*)sA + f1);
    gload16(&A[(m0 + rS2) * 1024 + k0 + cS2], (char*)sA + f2);
    gload16(&Bt[(n0 + rS1) * 1024 + k0 + cS1], (char*)sB + f1);
    gload16(&Bt[(n0 + rS2) * 1024 + k0 + cS2], (char*)sB + f2);
    __syncthreads();
    short8 af[4], bfv[4];
#pragma unroll
    for (int mf = 0; mf < 4; ++mf)
      af[mf] = *(const short8*)&sA[(wm * 64 + mf * 16 + lr) * 32 + lg * 8];
#pragma unroll
    for (int nf = 0; nf < 4; ++nf)
      bfv[nf] = *(const short8*)&sB[(wn * 64 + nf * 16 + lr) * 32 + lg * 8];
#pragma unroll
    for (int mf = 0; mf < 4; ++mf)
#pragma unroll
      for (int nf = 0; nf < 4; ++nf)
        acc[mf][nf] = __builtin_amdgcn_mfma_f32_16x16x32_bf16(af[mf], bfv[nf], acc[mf][nf], 0, 0, 0);
  }
  const int sec = n0 >> 10;  // 0=q 1=k 2=v (128 | 1024 so uniform per block)
  short* dst = sec == 0 ? qb : (sec == 1 ? kb : vb);
  const float scale = (sec == 0) ? 0.18033688011112042f : 1.0f;
#pragma unroll
  for (int mf = 0; mf < 4; ++mf) {
#pragma unroll
    for (int nf = 0; nf < 4; ++nf) {
      const int col = n0 + wn * 64 + nf * 16 + lr;
      const int w = col & 1023;
      const int h = w >> 6, d = w & 63;
#pragma unroll
      for (int r = 0; r < 4; ++r) {
        const int token = m0 + wm * 64 + mf * 16 + lg * 4 + r;
        const int b = token >> 11, s = token & 2047;
        dst[(((b << 4) | h) * 2048 + s) * 64 + d] = f2bf(acc[mf][nf][r] * scale);
      }
    }
  }
}

// ---------------- GEMM2: out = att @ Wproj + bias (fp32 out) ----------------
__global__ __launch_bounds__(256) void gemm_proj_kernel(
    const short* __restrict__ A, const short* __restrict__ Bt,
    const float* __restrict__ bias, float* __restrict__ out) {
  __shared__ short sA[128 * 32];
  __shared__ short sB[128 * 32];
  const int tid = threadIdx.x;
  const int lane = tid & 63, wid = tid >> 6;
  const int wm = wid >> 1, wn = wid & 1;
  const int lr = lane & 15, lg = lane >> 4;
  const int m0 = blockIdx.x * 128, n0 = blockIdx.y * 128;
  floatx4 acc[4][4] = {};
  const int f1 = tid * 16;
  const int rS1 = f1 >> 6, cS1 = (f1 & 63) >> 1;
  const int f2 = f1 + 4096;
  const int rS2 = f2 >> 6, cS2 = (f2 & 63) >> 1;
  for (int kt = 0; kt < 32; ++kt) {
    const int k0 = kt * 32;
    __syncthreads();
    gload16(&A[(m0 + rS1) * 1024 + k0 + cS1], (char*)sA + f1);
    gload16(&A[(m0 + rS2) * 1024 + k0 + cS2], (char*)sA + f2);
    gload16(&Bt[(n0 + rS1) * 1024 + k0 + cS1], (char*)sB + f1);
    gload16(&Bt[(n0 + rS2) * 1024 + k0 + cS2], (char*)sB + f2);
    __syncthreads();
    short8 af[4], bfv[4];
#pragma unroll
    for (int mf = 0; mf < 4; ++mf)
      af[mf] = *(const short8*)&sA[(wm * 64 + mf * 16 + lr) * 32 + lg * 8];
#pragma unroll
    for (int nf = 0; nf < 4; ++nf)
      bfv[nf] = *(const short8*)&sB[(wn * 64 + nf * 16 + lr) * 32 + lg * 8];
#pragma unroll
    for (int mf = 0; mf < 4; ++mf)
#pragma unroll
      for (int nf = 0; nf < 4; ++nf)
        acc[mf][nf] = __builtin_amdgcn_mfma_f32_16x16x32_bf16(af[mf], bfv[nf], acc[mf][nf], 0, 0, 0);
  }
#pragma unroll
  for (int mf = 0; mf < 4; ++mf) {
#pragma unroll
    for (int nf = 0; nf < 4; ++nf) {
      const int col = n0 + wn * 64 + nf * 16 + lr;
      const float bv = bias[col];
#pragma unroll
      for (int r = 0; r < 4; ++r) {
        const int row = m0 + wm * 64 + mf * 16 + lg * 4 + r;
        out[row * 1024 + col] = acc[mf][nf][r] + bv;
      }
    }
  }
}

// ---------------- Flash attention (causal), bf16 in/out ----------------
// v4: v2 geometry (512 blocks, 4 waves x 32 q-rows, qt paired with 15-qt ->
// uniform 34 KV tiles) + swapped QK^T (lane owns consecutive keys of one
// q-row): in-lane max + 2 shfl; P via v_cvt_pk_bf16_f32 + ds_write_b64;
// denominator via MFMA-with-ones; exp2 domain; defer-max (THR=8); skip
// fully-masked tiles per wave; dbuf K/VT staging; XCD swizzle.
__global__ __launch_bounds__(256) void attn_kernel(
    const short* __restrict__ qb, const short* __restrict__ kb,
    const short* __restrict__ vtb, short* __restrict__ attb) {
  __shared__ short sK[2][64 * 64];
  __shared__ short sVT[2][64 * 64];
  __shared__ short sP[4][32 * 64];
  const int tid = threadIdx.x;
  const int lane = tid & 63, wid = tid >> 6;
  const int lr = lane & 15, lg = lane >> 4;

  // XCD swizzle: each XCD's 64 blocks cover 8 consecutive bh (K/V in its L2).
  const int bid = blockIdx.x;                 // 0..511
  const int wgid = (bid & 7) * 64 + (bid >> 3);
  const int bh = wgid >> 3;                   // 0..63
  const int qx = wgid & 7;                    // 0..7

  const char* kbase = (const char*)(kb + bh * S_ * HD_);
  const char* vtbase = (const char*)(vtb + bh * HD_ * S_);
  const short* qbase = qb + bh * S_ * HD_;
  char* pbase = (char*)&sP[wid][0];
  const int b = bh >> 4, h = bh & 15;

  const int f1 = tid * 16;
  const int ro1 = f1 >> 7, cb1 = f1 & 127;
  const int sc1 = cb1 ^ ((ro1 & 7) << 4);
  const int f2 = f1 + 4096;
  const int ro2 = f2 >> 7, cb2 = f2 & 127;
  const int sc2 = cb2 ^ ((ro2 & 7) << 4);

  const int swz = (lr & 7) << 4;

  short8 vones;
#pragma unroll
  for (int j = 0; j < 8; ++j) vones[j] = (short)0x3F80;  // bf16 1.0

#pragma unroll 1
  for (int half = 0; half < 2; ++half) {
    const int qt = half ? (15 - qx) : qx;
    const int qw = qt * 128 + wid * 32;

    short8 qf[2][2];
#pragma unroll
    for (int qtile = 0; qtile < 2; ++qtile)
#pragma unroll
      for (int kf = 0; kf < 2; ++kf)
        qf[qtile][kf] = *(const short8*)&qbase[(qw + qtile * 16 + lr) * 64 + kf * 32 + lg * 8];

    floatx4 acc_o[2][4] = {};
    floatx4 acc_den[2] = {};
    float mrun[2] = {-1e30f, -1e30f};

    const int ntiles = 2 * qt + 2;

    // prologue: stage tile 0 into buf 0
    {
      char* dK = (char*)sK[0];
      char* dV = (char*)sVT[0];
      gload16(kbase + ro1 * 128 + sc1, dK + f1);
      gload16(kbase + ro2 * 128 + sc2, dK + f2);
      gload16(vtbase + ro1 * 4096 + sc1, dV + f1);
      gload16(vtbase + ro2 * 4096 + sc2, dV + f2);
      asm volatile("s_waitcnt vmcnt(0)" ::: "memory");
      __builtin_amdgcn_s_barrier();
      __builtin_amdgcn_sched_barrier(0);
    }

    int cur = 0;
#pragma unroll 1
    for (int t = 0; t < ntiles; ++t) {
      if (t + 1 < ntiles) {
        const int key0n = (t + 1) * 64;
        char* dK = (char*)sK[cur ^ 1];
        char* dV = (char*)sVT[cur ^ 1];
        gload16(kbase + (key0n + ro1) * 128 + sc1, dK + f1);
        gload16(kbase + (key0n + ro2) * 128 + sc2, dK + f2);
        gload16(vtbase + ro1 * 4096 + key0n * 2 + sc1, dV + f1);
        gload16(vtbase + ro2 * 4096 + key0n * 2 + sc2, dV + f2);
      }
      const int key0 = t * 64;
      if (key0 <= qw + 31) {  // wave-uniform: skip fully-masked tiles
        const char* cK = (const char*)sK[cur];
        const char* cV = (const char*)sVT[cur];

        // S^T = K Q^T : lane holds keys kt*16+lg*4+{0..3} of q-row (qtile*16+lr)
        floatx4 sT[4][2] = {};
        __builtin_amdgcn_s_setprio(1);
#pragma unroll
        for (int kt = 0; kt < 4; ++kt) {
#pragma unroll
          for (int kf = 0; kf < 2; ++kf) {
            short8 kfrag = *(const short8*)(cK + (kt * 16 + lr) * 128 + ((kf * 64 + lg * 16) ^ swz));
#pragma unroll
            for (int qtile = 0; qtile < 2; ++qtile)
              sT[kt][qtile] = __builtin_amdgcn_mfma_f32_16x16x32_bf16(kfrag, qf[qtile][kf], sT[kt][qtile], 0, 0, 0);
          }
        }
        __builtin_amdgcn_s_setprio(0);

        if (key0 + 63 > qw) {  // wave-uniform: diagonal tile, apply causal mask
#pragma unroll
          for (int kt = 0; kt < 4; ++kt)
#pragma unroll
            for (int qtile = 0; qtile < 2; ++qtile)
#pragma unroll
              for (int r = 0; r < 4; ++r)
                if (key0 + kt * 16 + lg * 4 + r > qw + qtile * 16 + lr) sT[kt][qtile][r] = -1e30f;
        }

        // per-q-row max: in-lane over 16 + butterfly across lg groups
        float mx[2], al[2];
        bool need = false;
#pragma unroll
        for (int qtile = 0; qtile < 2; ++qtile) {
          float m0v = fmaxf(fmaxf(sT[0][qtile][0], sT[0][qtile][1]), fmaxf(sT[0][qtile][2], sT[0][qtile][3]));
          float m1v = fmaxf(fmaxf(sT[1][qtile][0], sT[1][qtile][1]), fmaxf(sT[1][qtile][2], sT[1][qtile][3]));
          float m2v = fmaxf(fmaxf(sT[2][qtile][0], sT[2][qtile][1]), fmaxf(sT[2][qtile][2], sT[2][qtile][3]));
          float m3v = fmaxf(fmaxf(sT[3][qtile][0], sT[3][qtile][1]), fmaxf(sT[3][qtile][2], sT[3][qtile][3]));
          float m = fmaxf(fmaxf(m0v, m1v), fmaxf(m2v, m3v));
          m = fmaxf(m, __shfl_xor(m, 16));
          m = fmaxf(m, __shfl_xor(m, 32));
          mx[qtile] = m;
          need = need || (m > mrun[qtile] + 8.f);
        }
        if (__any(need)) {
#pragma unroll
          for (int qtile = 0; qtile < 2; ++qtile) {
            const float mnew = fmaxf(mrun[qtile], mx[qtile]);
            al[qtile] = __builtin_amdgcn_exp2f(mrun[qtile] - mnew);
            mrun[qtile] = mnew;
          }
          // broadcast alpha to O-orientation lanes (O row q = mf*16+lg*4+r -> al from lane lg*4+r)
#pragma unroll
          for (int mf = 0; mf < 2; ++mf) {
#pragma unroll
            for (int r = 0; r < 4; ++r) {
              const float alr = __shfl(al[mf], lg * 4 + r);
              acc_den[mf][r] *= alr;
#pragma unroll
              for (int nfd = 0; nfd < 4; ++nfd) acc_o[mf][nfd][r] *= alr;
            }
          }
        }

        // P = exp2(S - m) -> packed bf16 pairs -> ds_write_b64
#pragma unroll
        for (int kt = 0; kt < 4; ++kt) {
#pragma unroll
          for (int qtile = 0; qtile < 2; ++qtile) {
            const float p0 = __builtin_amdgcn_exp2f(sT[kt][qtile][0] - mrun[qtile]);
            const float p1 = __builtin_amdgcn_exp2f(sT[kt][qtile][1] - mrun[qtile]);
            const float p2 = __builtin_amdgcn_exp2f(sT[kt][qtile][2] - mrun[qtile]);
            const float p3 = __builtin_amdgcn_exp2f(sT[kt][qtile][3] - mrun[qtile]);
            unsigned lo, hi;
            asm("v_cvt_pk_bf16_f32 %0, %1, %2" : "=v"(lo) : "v"(p0), "v"(p1));
            asm("v_cvt_pk_bf16_f32 %0, %1, %2" : "=v"(hi) : "v"(p2), "v"(p3));
            *(unsigned long long*)(pbase + (qtile * 16 + lr) * 128 + ((kt * 32 + lg * 8) ^ swz)) =
                ((unsigned long long)hi << 32) | lo;
          }
        }

        // O += P @ V ; den += P @ 1
        __builtin_amdgcn_s_setprio(1);
#pragma unroll
        for (int kf2 = 0; kf2 < 2; ++kf2) {
          short8 pf[2];
#pragma unroll
          for (int mf = 0; mf < 2; ++mf) {
            pf[mf] = *(const short8*)(pbase + (mf * 16 + lr) * 128 + ((kf2 * 64 + lg * 16) ^ swz));
            acc_den[mf] = __builtin_amdgcn_mfma_f32_16x16x32_bf16(pf[mf], vones, acc_den[mf], 0, 0, 0);
          }
#pragma unroll
          for (int nfd = 0; nfd < 4; ++nfd) {
            short8 vfrag = *(const short8*)(cV + (nfd * 16 + lr) * 128 + ((kf2 * 64 + lg * 16) ^ swz));
#pragma unroll
            for (int mf = 0; mf < 2; ++mf)
              acc_o[mf][nfd] = __builtin_amdgcn_mfma_f32_16x16x32_bf16(pf[mf], vfrag, acc_o[mf][nfd], 0, 0, 0);
          }
        }
        __builtin_amdgcn_s_setprio(0);
      }

      __builtin_amdgcn_sched_barrier(0);
      asm volatile("s_waitcnt vmcnt(0)" ::: "memory");
      __builtin_amdgcn_s_barrier();
      __builtin_amdgcn_sched_barrier(0);
      cur ^= 1;
    }

    // epilogue -> att [token][h*64+d] bf16
#pragma unroll
    for (int mf = 0; mf < 2; ++mf) {
#pragma unroll
      for (int nfd = 0; nfd < 4; ++nfd) {
#pragma unroll
        for (int r = 0; r < 4; ++r) {
          const float o = acc_o[mf][nfd][r] / acc_den[mf][r];
          const int qrow = qw + mf * 16 + lg * 4 + r;
          const int d = nfd * 16 + lr;
          attb[(b * 2048 + qrow) * 1024 + h * 64 + d] = f2bf(o);
        }
      }
    }
  }
}

extern "C" void kernel_launch(void* const* d_in, const int* in_sizes, int n_in,
                              void* d_out, int out_size, void* d_ws, size_t ws_size,
                              hipStream_t stream) {
  (void)in_sizes; (void)n_in; (void)out_size; (void)ws_size;
  const float* x = (const float*)d_in[0];
  const float* Wqkv = (const float*)d_in[1];
  const float* Wproj = (const float*)d_in[2];
  const float* bproj = (const float*)d_in[3];
  float* out = (float*)d_out;

  char* w = (char*)d_ws;
  short* xb     = (short*)(w + 0);          // 16 MiB  [8192][1024]
  short* wqkvT  = (short*)(w + 16777216);   // 6 MiB   [3072][1024]
  short* wprojT = (short*)(w + 23068672);   // 2 MiB   [1024][1024]
  short* qb     = (short*)(w + 25165824);   // 16 MiB  [bh][s][d]
  short* kb     = (short*)(w + 41943040);   // 16 MiB
  short* vb     = (short*)(w + 58720256);   // 16 MiB
  short* vtb    = (short*)(w + 75497472);   // 16 MiB  [bh][d][s]
  short* attb   = (short*)(w + 92274688);   // 16 MiB  [8192][1024]

  cvt_x_kernel<<<4096, 256, 0, stream>>>(x, xb, TOK_ * D_ / 8);
  tconv_kernel<<<dim3(96, 32), dim3(32, 8), 0, stream>>>(Wqkv, wqkvT, 1024, 3072);
  tconv_kernel<<<dim3(32, 32), dim3(32, 8), 0, stream>>>(Wproj, wprojT, 1024, 1024);
  gemm_qkv_kernel<<<dim3(64, 24), 256, 0, stream>>>(xb, wqkvT, qb, kb, vb);
  tv_kernel<<<dim3(2, 64, 64), dim3(32, 8), 0, stream>>>(vb, vtb);
  attn_kernel<<<512, 256, 0, stream>>>(qb, kb, vtb, attb);
  gemm_proj_kernel<<<dim3(64, 8), 256, 0, stream>>>(attb, wprojT, bproj, out);
}